// Round 10
// baseline (8894.946 us; speedup 1.0000x reference)
//
#include <hip/hip_runtime.h>

// ============================================================================
// Conv2Seq round 9: R8 fragment-major layout + PLAIN cached loads for all
// mutable cross-block data (x planes, hbuf), coherence via R4's proven
// acquire/release __threadfence() in the distributed-slot barrier.
// R8 PMC: 64KB/CU/iter at 26 GB/s/CU = per-CU streaming ceiling, with ~50%
// of traffic being L2-bypassed duplicate x reads (atomics don't cache).
// Plain loads let L2 absorb the 16x per-XCD x duplication; L2-inv at the
// barrier is ~free since weights never fit L2 anyway (L3 is memory-side).
// ============================================================================

#define BB   32
#define TT   2048
#define DIN  64
#define HH   1024
#define DOUT 64
#define NSTEP 60
#define LL1  2045
#define LL2  2038
#define LL3  2023
#define CC1  8
#define CC2  16
#define CC3  32
#define K0   1120
#define K12  2080
#define KP0  1152     // 9 chunks of 128
#define KP12 2176     // 17 chunks of 128
#define NIT0  9
#define NIT12 17

typedef unsigned short u16;
typedef unsigned int   u32;
typedef unsigned long long u64;
typedef __attribute__((ext_vector_type(8))) short bf16x8;
typedef __attribute__((ext_vector_type(4))) float f32x4;

__device__ __forceinline__ float4 ld4(const float* p){ return *(const float4*)p; }
__device__ __forceinline__ u16 f2bf(float x){
  unsigned u = __float_as_uint(x);
  return (u16)((u + 0x7FFFu + ((u>>16)&1u)) >> 16);
}
__device__ __forceinline__ float bf2f(u16 h){ return __uint_as_float(((unsigned)h)<<16); }
__device__ __forceinline__ float bfq(u64 w, int i){
  return __uint_as_float(((u32)((w >> (16*i)) & 0xffffu)) << 16);
}
// atomics retained ONLY for the barrier words
__device__ __forceinline__ u32 lda32u(const u32* p){
  return __hip_atomic_load(p, __ATOMIC_RELAXED, __HIP_MEMORY_SCOPE_AGENT);
}
__device__ __forceinline__ void sta32(u32* p, u32 v){
  __hip_atomic_store(p, v, __ATOMIC_RELAXED, __HIP_MEMORY_SCOPE_AGENT);
}

// u32 slot index of pair (b, k) [k even] in a fragment-major x plane.
__device__ __forceinline__ u32 xidx(int NIT, int b, int k){
  int r = b & 15, xh = b >> 4;
  int it = k >> 7, kq = (k >> 5) & 3, q = (k >> 3) & 3, e = k & 7;
  return (u32)(((((xh*4 + kq)*NIT + it)*64) + q*16 + r)*4 + (e >> 1));
}

// ---------------------------------------------------------------------------
// conv kernels (one-shot; conv3 emits bf16 enc)
// ---------------------------------------------------------------------------
__global__ __launch_bounds__(256) void conv1_kernel(const float* __restrict__ x,
    const float* __restrict__ w, const float* __restrict__ bias,
    float* __restrict__ out){
  int idx = blockIdx.x*256 + threadIdx.x;
  if (idx >= BB*LL1) return;
  int b = idx / LL1, t = idx % LL1;
  float acc[CC1];
  #pragma unroll
  for (int c=0;c<CC1;++c) acc[c] = bias[c];
  for (int k=0;k<4;++k){
    const float* xr = x + ((size_t)(b*TT + t + k))*DIN;
    for (int d=0; d<DIN; d+=4){
      float4 v = ld4(xr + d);
      #pragma unroll
      for (int c=0;c<CC1;++c){
        acc[c] += v.x * w[((c*DIN+d  )<<2)+k]
                + v.y * w[((c*DIN+d+1)<<2)+k]
                + v.z * w[((c*DIN+d+2)<<2)+k]
                + v.w * w[((c*DIN+d+3)<<2)+k];
      }
    }
  }
  float* o = out + (size_t)idx*CC1;
  #pragma unroll
  for (int c=0;c<CC1;++c) o[c] = fmaxf(acc[c], 0.f);
}

__global__ __launch_bounds__(256) void conv2_kernel(const float* __restrict__ r1,
    const float* __restrict__ w, const float* __restrict__ bias,
    float* __restrict__ out){
  int idx = blockIdx.x*256 + threadIdx.x;
  if (idx >= BB*LL2) return;
  int b = idx / LL2, t = idx % LL2;
  float acc[CC2];
  #pragma unroll
  for (int c=0;c<CC2;++c) acc[c] = bias[c];
  for (int k=0;k<8;++k){
    const float* rr = r1 + ((size_t)(b*LL1 + t + k))*CC1;
    for (int c1=0;c1<CC1;c1+=4){
      float4 v = ld4(rr + c1);
      #pragma unroll
      for (int c=0;c<CC2;++c){
        acc[c] += v.x * w[((c*CC1+c1  )<<3)+k]
                + v.y * w[((c*CC1+c1+1)<<3)+k]
                + v.z * w[((c*CC1+c1+2)<<3)+k]
                + v.w * w[((c*CC1+c1+3)<<3)+k];
      }
    }
  }
  float* o = out + (size_t)idx*CC2;
  #pragma unroll
  for (int c=0;c<CC2;++c) o[c] = fmaxf(acc[c], 0.f);
}

__global__ __launch_bounds__(256) void conv3_kernel(const float* __restrict__ r2,
    const float* __restrict__ w, const float* __restrict__ bias,
    u16* __restrict__ out){
  int idx = blockIdx.x*256 + threadIdx.x;
  if (idx >= BB*LL3) return;
  int b = idx / LL3, t = idx % LL3;
  float acc[CC3];
  #pragma unroll
  for (int c=0;c<CC3;++c) acc[c] = bias[c];
  for (int k=0;k<16;++k){
    const float* rr = r2 + ((size_t)(b*LL2 + t + k))*CC2;
    for (int c2=0;c2<CC2;c2+=4){
      float4 v = ld4(rr + c2);
      #pragma unroll
      for (int c=0;c<CC3;++c){
        acc[c] += v.x * w[((c*CC2+c2  )<<4)+k]
                + v.y * w[((c*CC2+c2+1)<<4)+k]
                + v.z * w[((c*CC2+c2+2)<<4)+k]
                + v.w * w[((c*CC2+c2+3)<<4)+k];
      }
    }
  }
  u16* o = out + (size_t)idx*CC3;
  #pragma unroll
  for (int c=0;c<CC3;++c) o[c] = f2bf(fmaxf(acc[c], 0.f));
}

// ---------------------------------------------------------------------------
// weight prep, FRAGMENT-MAJOR (unchanged from R8)
// ---------------------------------------------------------------------------
__global__ __launch_bounds__(256) void prep_kernel(const float* __restrict__ wih,
    const float* __restrict__ whh, u16* __restrict__ wh, u16* __restrict__ wl,
    int Kih, int Kin, int NIT){
  const size_t total = (size_t)128*2*4*NIT*64;
  for (size_t E = (size_t)blockIdx.x*256 + threadIdx.x; E < total;
       E += (size_t)gridDim.x*256){
    int lane = (int)(E & 63);
    size_t t1 = E >> 6;
    int it = (int)(t1 % NIT);  t1 /= NIT;
    int kq = (int)(t1 & 3);    t1 >>= 2;
    int wt = (int)(t1 & 1);    int bid = (int)(t1 >> 1);
    int r = lane & 15, q = lane >> 4;
    int R = bid*32 + wt*16 + r;
    int rl = R & 31, gate = rl >> 3, jj = rl & 7;
    int grow = gate*1024 + (R >> 5)*8 + jj;
    int k0 = it*128 + kq*32 + q*8;
    u16 hv[8], lv[8];
    #pragma unroll
    for (int e=0; e<8; ++e){
      int k = k0 + e;
      float v = 0.f;
      if (k < Kih)      v = wih[(size_t)grow*Kih + k];
      else if (k < Kin) v = whh[(size_t)grow*HH + (k - Kih)];
      u16 h = f2bf(v);
      hv[e] = h;
      lv[e] = f2bf(v - bf2f(h));
    }
    *(ulonglong2*)(wh + E*8) = *(ulonglong2*)hv;
    *(ulonglong2*)(wl + E*8) = *(ulonglong2*)lv;
  }
}

__global__ __launch_bounds__(256) void bsum_kernel(
    const float* __restrict__ bih1, const float* __restrict__ bhh1,
    const float* __restrict__ bih2, const float* __restrict__ bhh2,
    const float* __restrict__ bih3, const float* __restrict__ bhh3,
    float* __restrict__ bs0, float* __restrict__ bs1, float* __restrict__ bs2){
  int idx = blockIdx.x*256 + threadIdx.x;
  if (idx < 4096)       bs0[idx] = bih1[idx] + bhh1[idx];
  else if (idx < 8192){ int r=idx-4096; bs1[r] = bih2[r] + bhh2[r]; }
  else if (idx < 12288){int r=idx-8192; bs2[r] = bih3[r] + bhh3[r]; }
}

__global__ void barinit_kernel(u32* bar){
  for (int i = threadIdx.x; i < 512; i += 256) bar[i] = 0u;
}

// ---------------------------------------------------------------------------
struct SeqArgs {
  const float *x;
  const float *wa[3];
  const float *wout, *bout;
  const u16 *enc;
  const u16 *wwh[3], *wwl[3];
  const float *bsum[3];
  u16 *pl[3][2][2];            // fragment-major x planes (plain access now)
  float *hbuf;
  float *cbuf;
  float *dout;
  u32 *slots;
  u32 *go;
};

#define SMEM_FLOATS 5376

// distributed-slot grid barrier with R4-style release/acquire fences.
// Release: threadfence (wb dirty L2) before arrival; Acquire: threadfence
// (inv L1/L2) after the spin, before any reads of others' data.
__device__ __forceinline__ void gbar(const SeqArgs& A, u32 nb){
  asm volatile("s_waitcnt vmcnt(0)" ::: "memory");
  __syncthreads();
  const int bid = blockIdx.x, tid = threadIdx.x;
  if (tid == 0){
    __threadfence();   // release: push this block's plain stores to coherent pt
    __hip_atomic_store(A.slots + bid, nb, __ATOMIC_RELEASE,
                       __HIP_MEMORY_SCOPE_AGENT);
  }
  if (bid == 0){
    if (tid < 64){
      for (;;){
        u32 v0 = lda32u(A.slots + tid);
        u32 v1 = lda32u(A.slots + 64 + tid);
        u32 v2 = lda32u(A.slots + 128 + tid);
        u32 v3 = lda32u(A.slots + 192 + tid);
        u32 mn = min(min(v0,v1), min(v2,v3));
        if (__all(mn >= nb)) break;
        __builtin_amdgcn_s_sleep(4);
      }
      if (tid == 0) sta32(A.go, nb);
    }
  } else if (tid == 0){
    while (lda32u(A.go) < nb) __builtin_amdgcn_s_sleep(4);
  }
  if (tid == 0) __threadfence();   // acquire: invalidate stale L1/L2 lines
  __syncthreads();
}

// attend for (l,b) parity par: q = wa^T h ; softmax(enc.q) ; ctx -> plane
__device__ void attend_phase(const SeqArgs& A, int l, int par, int b, float* sm){
  const int tid = threadIdx.x;
  const float* wa = A.wa[l];
  const float* h  = A.hbuf + (size_t)((l*2+par)*BB + b)*HH;
  const int NITl = (l==0)? NIT0 : NIT12;
  u16* ch = A.pl[l][par][0];
  u16* cl = A.pl[l][par][1];
  float* sh  = sm;
  float* sq  = sm + 1024;
  float* ss  = sm + 1056;
  float* red = sm + 3104;
  float* ctxf= sm + 4128;

  sh[tid] = h[tid];
  __syncthreads();

  const int cc = tid&31, g = tid>>5;
  float part = 0.f;
  for (int kk=g; kk<HH; kk+=32) part += wa[kk*32+cc]*sh[kk];
  red[tid] = part; __syncthreads();
  if (tid<32){ float s=0.f;
    #pragma unroll
    for (int gg=0; gg<32; ++gg) s += red[gg*32+tid];
    sq[tid]=s; }
  __syncthreads();

  const u16* eb = A.enc + (size_t)b*LL3*CC3;
  float lmax = -1e30f;
  for (int t=tid; t<LL3; t+=1024){
    const u16* er = eb + t*32; float dot=0.f;
    #pragma unroll
    for (int c4=0;c4<8;++c4){
      u64 w = *(const u64*)(er + c4*4);
      dot += bfq(w,0)*sq[c4*4] + bfq(w,1)*sq[c4*4+1]
           + bfq(w,2)*sq[c4*4+2] + bfq(w,3)*sq[c4*4+3];
    }
    ss[t]=dot; lmax=fmaxf(lmax,dot);
  }
  #pragma unroll
  for (int o=32;o>0;o>>=1) lmax = fmaxf(lmax, __shfl_xor(lmax,o));
  if ((tid&63)==0) red[tid>>6] = lmax;
  __syncthreads();
  if (tid==0){ float m=red[0]; for (int w=1;w<16;++w) m=fmaxf(m,red[w]); red[16]=m; }
  __syncthreads();
  const float m = red[16];

  float lsum = 0.f;
  for (int t=tid; t<LL3; t+=1024){ float e=__expf(ss[t]-m); ss[t]=e; lsum+=e; }
  #pragma unroll
  for (int o=32;o>0;o>>=1) lsum += __shfl_xor(lsum,o);
  if ((tid&63)==0) red[32 + (tid>>6)] = lsum;
  __syncthreads();
  if (tid==0){ float z=0.f; for (int w=0;w<16;++w) z+=red[32+w]; red[17]=1.0f/z; }
  __syncthreads();
  const float rZ = red[17];

  float acc = 0.f;
  for (int t=g; t<LL3; t+=32) acc += ss[t]*bf2f(eb[t*32+cc]);
  __syncthreads();
  red[tid] = acc; __syncthreads();
  if (tid<32){ float s=0.f;
    #pragma unroll
    for (int gg=0; gg<32; ++gg) s += red[gg*32+tid];
    ctxf[tid] = s*rZ; }
  __syncthreads();
  if (tid < 16){
    float v0=ctxf[2*tid], v1=ctxf[2*tid+1];
    ((u32*)ch)[xidx(NITl, b, 2*tid)] = (u32)f2bf(v0) | ((u32)f2bf(v1)<<16);
  } else if (tid < 32){
    int t2 = tid-16;
    float v0=ctxf[2*t2], v1=ctxf[2*t2+1];
    u16 h0=f2bf(v0), h1=f2bf(v1);
    ((u32*)cl)[xidx(NITl, b, 2*t2)] =
        (u32)f2bf(v0-bf2f(h0)) | ((u32)f2bf(v1-bf2f(h1))<<16);
  }
}

// out phase: y(s) -> dout[:,s,:]; y -> prev slot (k=32..96) of l0 plane pn.
__device__ void out_phase(const SeqArgs& A, int pn, int s, int b, float* sm){
  float* sh = sm; float* red = sm+1024; float* yv = sm+2048;
  const int tid = threadIdx.x;
  sh[tid] = A.hbuf[(size_t)((2*2+pn)*BB + b)*HH + tid];
  __syncthreads();
  const int d = tid&63, kg = tid>>6;
  const float* wr = A.wout + (size_t)d*HH + kg*64;
  const float* hh = sh + kg*64;
  float acc = 0.f;
  #pragma unroll
  for (int k=0;k<64;k+=4){ float4 w4=ld4(wr+k); float4 hv=*(const float4*)&hh[k];
    acc += w4.x*hv.x+w4.y*hv.y+w4.z*hv.z+w4.w*hv.w; }
  red[tid]=acc; __syncthreads();
  if (tid<64){
    float y = A.bout[tid];
    #pragma unroll
    for (int kk=0;kk<16;++kk) y += red[kk*64+tid];
    A.dout[((size_t)b*NSTEP+s)*DOUT+tid] = y;
    yv[tid] = y;
  }
  __syncthreads();
  if (tid < 32){
    float v0=yv[2*tid], v1=yv[2*tid+1];
    ((u32*)A.pl[0][pn][0])[xidx(NIT0, b, 32 + 2*tid)] =
        (u32)f2bf(v0) | ((u32)f2bf(v1)<<16);
  } else if (tid < 64){
    int t2 = tid-32;
    float v0=yv[2*t2], v1=yv[2*t2+1];
    u16 h0=f2bf(v0), h1=f2bf(v1);
    ((u32*)A.pl[0][pn][1])[xidx(NIT0, b, 32 + 2*t2)] =
        (u32)f2bf(v0-bf2f(h0)) | ((u32)f2bf(v1-bf2f(h1))<<16);
  }
}

// MFMA GEMM + fused cell. Fragment-major; ALL loads plain & cached now
// (coherence guaranteed by gbar's acquire fence).
template<int L, int NIT>
__device__ void gemm_phase(const SeqArgs& A, int p, int pn, float* sm){
  const int bid = blockIdx.x, tid = threadIdx.x;
  const u16* wh  = A.wwh[L];
  const u16* wlo = A.wwl[L];
  const u16* ih = A.pl[L][p][0];
  const u16* il = A.pl[L][p][1];
  const int wave = tid>>6, lane = tid&63;
  const int wt = wave>>3, xh = (wave>>2)&1, kq = wave&3;
  const size_t wbase = ((((size_t)bid*2 + wt)*4 + kq)*NIT)*512 + lane*8;
  const size_t xbase = (((size_t)xh*4 + kq)*NIT)*512 + lane*8;
  const u16* wph = wh  + wbase;
  const u16* wpl = wlo + wbase;
  const u16* xb  = ih + xbase;
  const u16* xlb = il + xbase;

  f32x4 acc0 = {0.f,0.f,0.f,0.f}, acc1 = {0.f,0.f,0.f,0.f}, acc2 = {0.f,0.f,0.f,0.f};
  bf16x8 whA, wlA, whB, wlB, xhA, xlA, xhB, xlB;
  whA = *(const bf16x8*)(wph);
  wlA = *(const bf16x8*)(wpl);
  xhA = *(const bf16x8*)(xb);
  xlA = *(const bf16x8*)(xlb);
  #pragma unroll
  for (int it = 0; it < NIT; ++it){
    const int o = (it+1)*512;
    if ((it & 1) == 0){
      if (it+1 < NIT){
        whB = *(const bf16x8*)(wph + o);
        wlB = *(const bf16x8*)(wpl + o);
        xhB = *(const bf16x8*)(xb + o);
        xlB = *(const bf16x8*)(xlb + o);
      }
      acc0 = __builtin_amdgcn_mfma_f32_16x16x32_bf16(xhA, whA, acc0, 0,0,0);
      acc1 = __builtin_amdgcn_mfma_f32_16x16x32_bf16(xlA, whA, acc1, 0,0,0);
      acc2 = __builtin_amdgcn_mfma_f32_16x16x32_bf16(xhA, wlA, acc2, 0,0,0);
    } else {
      if (it+1 < NIT){
        whA = *(const bf16x8*)(wph + o);
        wlA = *(const bf16x8*)(wpl + o);
        xhA = *(const bf16x8*)(xb + o);
        xlA = *(const bf16x8*)(xlb + o);
      }
      acc0 = __builtin_amdgcn_mfma_f32_16x16x32_bf16(xhB, whB, acc0, 0,0,0);
      acc1 = __builtin_amdgcn_mfma_f32_16x16x32_bf16(xlB, whB, acc1, 0,0,0);
      acc2 = __builtin_amdgcn_mfma_f32_16x16x32_bf16(xhB, wlB, acc2, 0,0,0);
    }
  }
  f32x4 acc = acc0 + acc1 + acc2;

  float* red = sm;            // 16*256
  float* sg  = sm + 4096;     // 32*32
  float* hv  = sm + 5120;     // 8*32
  #pragma unroll
  for (int rg=0; rg<4; ++rg) red[wave*256 + lane*4 + rg] = acc[rg];
  __syncthreads();
  {
    const int tile = tid>>8, e = tid&255;
    const int wt2 = tile>>1, xh2 = tile&1;
    const int base = (wt2*8 + xh2*4)*256 + e;
    float v = red[base] + red[base+256] + red[base+512] + red[base+768];
    const int ln = e>>2, rg = e&3;
    // D layout (m89): col=lane&15 -> weight row, row=4*(lane>>4)+reg -> batch
    sg[(wt2*16 + (ln&15))*32 + xh2*16 + ((ln>>4)<<2) + rg] = v;
  }
  __syncthreads();
  if (tid < 256){
    const int b = tid&31, jj = tid>>5;
    const int j = bid*8 + jj;
    const float* bs = A.bsum[L];
    float gi = sg[(0 +jj)*32+b] + bs[j];
    float gf = sg[(8 +jj)*32+b] + bs[1024+j];
    float gg = sg[(16+jj)*32+b] + bs[2048+j];
    float go = sg[(24+jj)*32+b] + bs[3072+j];
    float i_ = 1.f/(1.f+__expf(-gi));
    float f_ = 1.f/(1.f+__expf(-gf));
    float g_ = tanhf(gg);
    float o_ = 1.f/(1.f+__expf(-go));
    float* cb = A.cbuf + ((size_t)L*BB + b)*HH + j;
    float c = f_*cb[0] + i_*g_;
    cb[0] = c;
    float hval = o_*tanhf(c);
    A.hbuf[((size_t)(L*2+pn)*BB + b)*HH + j] = hval;
    hv[jj*32 + b] = hval;
  }
  __syncthreads();
  if (tid < 128){
    const int b = tid&31, pr = tid>>5;
    const int jj0 = pr*2;
    float v0 = hv[jj0*32+b], v1 = hv[(jj0+1)*32+b];
    u16 h0 = f2bf(v0), h1 = f2bf(v1);
    u32 ph  = (u32)h0 | ((u32)h1<<16);
    u32 plq = (u32)f2bf(v0-bf2f(h0)) | ((u32)f2bf(v1-bf2f(h1))<<16);
    const int col = bid*8 + jj0;
    if (L == 0){
      u32 i1 = xidx(NIT0,  b, 96 + col);     // own h1, next step
      ((u32*)A.pl[0][pn][0])[i1] = ph;  ((u32*)A.pl[0][pn][1])[i1] = plq;
      u32 i2 = xidx(NIT12, b, 32 + col);     // L2 input, this step
      ((u32*)A.pl[1][p ][0])[i2] = ph;  ((u32*)A.pl[1][p ][1])[i2] = plq;
    } else if (L == 1){
      u32 i1 = xidx(NIT12, b, 1056 + col);   // own h2, next step
      ((u32*)A.pl[1][pn][0])[i1] = ph;  ((u32*)A.pl[1][pn][1])[i1] = plq;
      u32 i2 = xidx(NIT12, b, 32 + col);     // L3 input, this step
      ((u32*)A.pl[2][p ][0])[i2] = ph;  ((u32*)A.pl[2][p ][1])[i2] = plq;
    } else {
      u32 i1 = xidx(NIT12, b, 1056 + col);   // own h3, next step
      ((u32*)A.pl[2][pn][0])[i1] = ph;  ((u32*)A.pl[2][pn][1])[i1] = plq;
    }
  }
}

__global__ __launch_bounds__(1024, 4) void seq_kernel(SeqArgs A){
  __shared__ float sm[SMEM_FLOATS];
  const int bid = blockIdx.x, tid = threadIdx.x;
  const size_t gid = (size_t)bid*1024 + tid;
  const size_t gstr = (size_t)256*1024;
  u32 nb = 0;

  // ---- init: zero ALL planes, hbuf par0, cbuf ----
  {
    const size_t n0 = (size_t)32*(KP0>>1);
    const size_t n1 = (size_t)32*(KP12>>1);
    for (size_t i = gid; i < n0; i += gstr){
      #pragma unroll
      for (int q=0;q<2;++q)
        #pragma unroll
        for (int hl=0;hl<2;++hl)
          ((u32*)A.pl[0][q][hl])[i] = 0u;
    }
    for (size_t i = gid; i < n1; i += gstr){
      #pragma unroll
      for (int q=0;q<2;++q)
        #pragma unroll
        for (int hl=0;hl<2;++hl){
          ((u32*)A.pl[1][q][hl])[i] = 0u;
          ((u32*)A.pl[2][q][hl])[i] = 0u;
        }
    }
  }
  for (size_t i = gid; i < (size_t)3*32*1024; i += gstr){
    size_t l2 = i >> 15, r = i & 32767, b = r >> 10, j = r & 1023;
    A.hbuf[((l2*2+0)*BB + b)*HH + j] = 0.f;
  }
  if (bid < 128){
    for (int t = tid; t < 3*32*8; t += 1024){
      int l2 = t/(32*8), r = t%(32*8), b = r>>3, jj = r&7;
      A.cbuf[((size_t)l2*BB + b)*HH + bid*8 + jj] = 0.f;
    }
  }
  gbar(A, ++nb);

  // P0: att1/2/3(0) at parity 0 ; prev(0) = x[:,T-1,:] into l0 plane par0.
  if (bid >= 128 && bid < 224){
    int l = (bid-128)>>5, b = (bid-128)&31;
    attend_phase(A, l, 0, b, sm);
  } else if (bid >= 224){
    int b = bid - 224;
    if (tid < 64 && (tid & 1) == 0){
      float v  = A.x[((size_t)b*TT + (TT-1))*DIN + tid];
      float v1 = A.x[((size_t)b*TT + (TT-1))*DIN + tid + 1];
      u16 h = f2bf(v), h1 = f2bf(v1);
      u32 idx = xidx(NIT0, b, 32 + tid);
      ((u32*)A.pl[0][0][0])[idx] = (u32)h | ((u32)h1<<16);
      u16 l0 = f2bf(v - bf2f(h)), l1 = f2bf(v1 - bf2f(h1));
      ((u32*)A.pl[0][0][1])[idx] = (u32)l0 | ((u32)l1<<16);
    }
  }
  gbar(A, ++nb);

  for (int s = 0; s < NSTEP; ++s){
    const int p = s&1, pn = p^1;
    // P1: G1(s)
    if (bid < 128) gemm_phase<0,NIT0>(A, p, pn, sm);
    gbar(A, ++nb);
    // P2: G2(s) || att1(s+1)
    if (bid < 128)        gemm_phase<1,NIT12>(A, p, pn, sm);
    else if (bid < 160)   attend_phase(A, 0, pn, bid-128, sm);
    gbar(A, ++nb);
    // P3: G3(s) || att2(s+1)
    if (bid < 128)        gemm_phase<2,NIT12>(A, p, pn, sm);
    else if (bid < 160)   attend_phase(A, 1, pn, bid-128, sm);
    gbar(A, ++nb);
    // P4: out(s) || att3(s+1)
    if (bid >= 128 && bid < 160)      out_phase(A, pn, s, bid-128, sm);
    else if (bid >= 160 && bid < 192) attend_phase(A, 2, pn, bid-160, sm);
    gbar(A, ++nb);
  }
}

// ---------------------------------------------------------------------------
extern "C" void kernel_launch(void* const* d_in, const int* in_sizes, int n_in,
                              void* d_out, int out_size, void* d_ws, size_t ws_size,
                              hipStream_t stream) {
  const float* x    = (const float*)d_in[0];
  const float* w_c1 = (const float*)d_in[1];
  const float* b_c1 = (const float*)d_in[2];
  const float* w_c2 = (const float*)d_in[3];
  const float* b_c2 = (const float*)d_in[4];
  const float* w_c3 = (const float*)d_in[5];
  const float* b_c3 = (const float*)d_in[6];

  SeqArgs A;
  A.x     = x;
  A.wa[0] = (const float*)d_in[7];
  A.wa[1] = (const float*)d_in[9];
  A.wa[2] = (const float*)d_in[11];
  const float* wih1 = (const float*)d_in[13];
  const float* whh1 = (const float*)d_in[14];
  const float* bih1 = (const float*)d_in[15];
  const float* bhh1 = (const float*)d_in[16];
  const float* wih2 = (const float*)d_in[17];
  const float* whh2 = (const float*)d_in[18];
  const float* bih2 = (const float*)d_in[19];
  const float* bhh2 = (const float*)d_in[20];
  const float* wih3 = (const float*)d_in[21];
  const float* whh3 = (const float*)d_in[22];
  const float* bih3 = (const float*)d_in[23];
  const float* bhh3 = (const float*)d_in[24];
  A.wout = (const float*)d_in[25];
  A.bout = (const float*)d_in[26];
  A.dout = (float*)d_out;

  char* base = (char*)d_ws;
  size_t off = 0;
  auto alloc = [&](size_t bytes)->char*{
    char* pp = base + off; off = (off + bytes + 255) & ~(size_t)255; return pp;
  };

  u16* enc = (u16*)alloc((size_t)BB*LL3*CC3*2);
  A.enc  = enc;
  A.hbuf = (float*)alloc((size_t)3*2*BB*HH*4);
  A.cbuf = (float*)alloc((size_t)3*BB*HH*4);
  for (int l=0;l<3;++l){
    size_t kp = (l==0)? KP0 : KP12;
    for (int par=0; par<2; ++par)
      for (int hl=0; hl<2; ++hl)
        A.pl[l][par][hl] = (u16*)alloc((size_t)BB*kp*2);
  }
  float* bs0 = (float*)alloc(4096*4);
  float* bs1 = (float*)alloc(4096*4);
  float* bs2 = (float*)alloc(4096*4);
  A.bsum[0]=bs0; A.bsum[1]=bs1; A.bsum[2]=bs2;
  u32* bar = (u32*)alloc(4096);
  A.slots = bar;
  A.go    = bar + 320;
  u16 *wp[6];
  wp[0] = (u16*)alloc((size_t)4096*KP0*2);
  wp[1] = (u16*)alloc((size_t)4096*KP0*2);
  wp[2] = (u16*)alloc((size_t)4096*KP12*2);
  wp[3] = (u16*)alloc((size_t)4096*KP12*2);
  wp[4] = (u16*)alloc((size_t)4096*KP12*2);
  wp[5] = (u16*)alloc((size_t)4096*KP12*2);
  A.wwh[0]=wp[0]; A.wwl[0]=wp[1];
  A.wwh[1]=wp[2]; A.wwl[1]=wp[3];
  A.wwh[2]=wp[4]; A.wwl[2]=wp[5];

  // conv temps alias the layer-1 hi weight buffer (preps run after convs)
  float* r1 = (float*)wp[0];
  float* r2 = (float*)(((char*)wp[0]) + 2095104);

  conv1_kernel<<<(BB*LL1+255)/256, 256, 0, stream>>>(x, w_c1, b_c1, r1);
  conv2_kernel<<<(BB*LL2+255)/256, 256, 0, stream>>>(r1, w_c2, b_c2, r2);
  conv3_kernel<<<(BB*LL3+255)/256, 256, 0, stream>>>(r2, w_c3, b_c3, enc);
  prep_kernel<<<2048, 256, 0, stream>>>(wih1, whh1, wp[0], wp[1],   96, K0,  NIT0);
  prep_kernel<<<2048, 256, 0, stream>>>(wih2, whh2, wp[2], wp[3], 1056, K12, NIT12);
  prep_kernel<<<2048, 256, 0, stream>>>(wih3, whh3, wp[4], wp[5], 1056, K12, NIT12);
  bsum_kernel<<<48, 256, 0, stream>>>(bih1,bhh1,bih2,bhh2,bih3,bhh3, bs0,bs1,bs2);
  barinit_kernel<<<1, 256, 0, stream>>>(bar);

  void* params[] = { (void*)&A };
  hipLaunchCooperativeKernel((const void*)seq_kernel, dim3(256), dim3(1024),
                             params, 0, stream);
}

// Round 11
// 4919.790 us; speedup vs baseline: 1.8080x; 1.8080x over previous
//
#include <hip/hip_runtime.h>

// ============================================================================
// Conv2Seq round 10: R8 + ALL-256-block GEMM (16 rows/block, was 32x128 with
// half the machine idle-spinning). Schedule: P1 G1(256) P2 G2(256) P3 G3(256)
// P4 [att1|att2|att3](s+1) + out(s) on 128 blocks. R8 PMC showed time ==
// weight-stream time at 868 GB/s on 128 CUs; doubling streaming CUs should
// ~halve G phases. Fragment-major layout, fence-free barrier, x via agent
// atomics, 1-ahead prefetch -- all R8 verbatim.
// ============================================================================

#define BB   32
#define TT   2048
#define DIN  64
#define HH   1024
#define DOUT 64
#define NSTEP 60
#define LL1  2045
#define LL2  2038
#define LL3  2023
#define CC1  8
#define CC2  16
#define CC3  32
#define K0   1120
#define K12  2080
#define KP0  1280     // 8 kq * NIT0(5) * 32
#define KP12 2304     // 8 kq * NIT12(9) * 32
#define NIT0  5
#define NIT12 9

typedef unsigned short u16;
typedef unsigned int   u32;
typedef unsigned long long u64;
typedef __attribute__((ext_vector_type(8))) short bf16x8;
typedef __attribute__((ext_vector_type(4))) float f32x4;

union FR { u64 q[2]; bf16x8 v; };

__device__ __forceinline__ float4 ld4(const float* p){ return *(const float4*)p; }
__device__ __forceinline__ u16 f2bf(float x){
  unsigned u = __float_as_uint(x);
  return (u16)((u + 0x7FFFu + ((u>>16)&1u)) >> 16);
}
__device__ __forceinline__ float bf2f(u16 h){ return __uint_as_float(((unsigned)h)<<16); }
__device__ __forceinline__ float bfq(u64 w, int i){
  return __uint_as_float(((u32)((w >> (16*i)) & 0xffffu)) << 16);
}
// coherent-point accessors (bypass stale L1/L2) for cross-block mutable data
__device__ __forceinline__ float lda32f(const float* p){
  return __hip_atomic_load(p, __ATOMIC_RELAXED, __HIP_MEMORY_SCOPE_AGENT);
}
__device__ __forceinline__ u32 lda32u(const u32* p){
  return __hip_atomic_load(p, __ATOMIC_RELAXED, __HIP_MEMORY_SCOPE_AGENT);
}
__device__ __forceinline__ u64 lda64(const void* p){
  return __hip_atomic_load((const u64*)p, __ATOMIC_RELAXED, __HIP_MEMORY_SCOPE_AGENT);
}
__device__ __forceinline__ void sta32(u32* p, u32 v){
  __hip_atomic_store(p, v, __ATOMIC_RELAXED, __HIP_MEMORY_SCOPE_AGENT);
}
__device__ __forceinline__ void sta32f(float* p, float v){
  __hip_atomic_store(p, v, __ATOMIC_RELAXED, __HIP_MEMORY_SCOPE_AGENT);
}

// u32 slot index of pair (b, k) [k even] in a fragment-major x plane.
// entry = ((xh*8 + kq)*NIT + it)*64 + q*16 + r ; 4 u32 per entry.
// k = (kq*NIT + it)*32 + q*8 + e
__device__ __forceinline__ u32 xidx(int NIT, int b, int k){
  int r = b & 15, xh = b >> 4;
  int c = k >> 5;
  int kq = c / NIT, it = c - kq*NIT;
  int q = (k >> 3) & 3, e = k & 7;
  return (u32)((((xh*8 + kq)*NIT + it)*64 + q*16 + r)*4 + (e >> 1));
}

// ---------------------------------------------------------------------------
// conv kernels (one-shot; conv3 emits bf16 enc)
// ---------------------------------------------------------------------------
__global__ __launch_bounds__(256) void conv1_kernel(const float* __restrict__ x,
    const float* __restrict__ w, const float* __restrict__ bias,
    float* __restrict__ out){
  int idx = blockIdx.x*256 + threadIdx.x;
  if (idx >= BB*LL1) return;
  int b = idx / LL1, t = idx % LL1;
  float acc[CC1];
  #pragma unroll
  for (int c=0;c<CC1;++c) acc[c] = bias[c];
  for (int k=0;k<4;++k){
    const float* xr = x + ((size_t)(b*TT + t + k))*DIN;
    for (int d=0; d<DIN; d+=4){
      float4 v = ld4(xr + d);
      #pragma unroll
      for (int c=0;c<CC1;++c){
        acc[c] += v.x * w[((c*DIN+d  )<<2)+k]
                + v.y * w[((c*DIN+d+1)<<2)+k]
                + v.z * w[((c*DIN+d+2)<<2)+k]
                + v.w * w[((c*DIN+d+3)<<2)+k];
      }
    }
  }
  float* o = out + (size_t)idx*CC1;
  #pragma unroll
  for (int c=0;c<CC1;++c) o[c] = fmaxf(acc[c], 0.f);
}

__global__ __launch_bounds__(256) void conv2_kernel(const float* __restrict__ r1,
    const float* __restrict__ w, const float* __restrict__ bias,
    float* __restrict__ out){
  int idx = blockIdx.x*256 + threadIdx.x;
  if (idx >= BB*LL2) return;
  int b = idx / LL2, t = idx % LL2;
  float acc[CC2];
  #pragma unroll
  for (int c=0;c<CC2;++c) acc[c] = bias[c];
  for (int k=0;k<8;++k){
    const float* rr = r1 + ((size_t)(b*LL1 + t + k))*CC1;
    for (int c1=0;c1<CC1;c1+=4){
      float4 v = ld4(rr + c1);
      #pragma unroll
      for (int c=0;c<CC2;++c){
        acc[c] += v.x * w[((c*CC1+c1  )<<3)+k]
                + v.y * w[((c*CC1+c1+1)<<3)+k]
                + v.z * w[((c*CC1+c1+2)<<3)+k]
                + v.w * w[((c*CC1+c1+3)<<3)+k];
      }
    }
  }
  float* o = out + (size_t)idx*CC2;
  #pragma unroll
  for (int c=0;c<CC2;++c) o[c] = fmaxf(acc[c], 0.f);
}

__global__ __launch_bounds__(256) void conv3_kernel(const float* __restrict__ r2,
    const float* __restrict__ w, const float* __restrict__ bias,
    u16* __restrict__ out){
  int idx = blockIdx.x*256 + threadIdx.x;
  if (idx >= BB*LL3) return;
  int b = idx / LL3, t = idx % LL3;
  float acc[CC3];
  #pragma unroll
  for (int c=0;c<CC3;++c) acc[c] = bias[c];
  for (int k=0;k<16;++k){
    const float* rr = r2 + ((size_t)(b*LL2 + t + k))*CC2;
    for (int c2=0;c2<CC2;c2+=4){
      float4 v = ld4(rr + c2);
      #pragma unroll
      for (int c=0;c<CC3;++c){
        acc[c] += v.x * w[((c*CC2+c2  )<<4)+k]
                + v.y * w[((c*CC2+c2+1)<<4)+k]
                + v.z * w[((c*CC2+c2+2)<<4)+k]
                + v.w * w[((c*CC2+c2+3)<<4)+k];
      }
    }
  }
  u16* o = out + (size_t)idx*CC3;
  #pragma unroll
  for (int c=0;c<CC3;++c) o[c] = f2bf(fmaxf(acc[c], 0.f));
}

// ---------------------------------------------------------------------------
// weight prep, FRAGMENT-MAJOR for 16-row blocks:
// E = ((bid*8 + kq)*NIT + it)*64 + lane; lane = q*16 + r.
// row R = bid*16 + r; rl = R&15; gate = rl>>2; jj = rl&3;
// grow = gate*1024 + bid*4 + jj; k = (kq*NIT+it)*32 + q*8 + e.
// ---------------------------------------------------------------------------
__global__ __launch_bounds__(256) void prep_kernel(const float* __restrict__ wih,
    const float* __restrict__ whh, u16* __restrict__ wh, u16* __restrict__ wl,
    int Kih, int Kin, int NIT){
  const size_t total = (size_t)256*8*NIT*64;
  for (size_t E = (size_t)blockIdx.x*256 + threadIdx.x; E < total;
       E += (size_t)gridDim.x*256){
    int lane = (int)(E & 63);
    size_t t1 = E >> 6;
    int it = (int)(t1 % NIT);  t1 /= NIT;
    int kq = (int)(t1 & 7);    int bid = (int)(t1 >> 3);
    int r = lane & 15, q = lane >> 4;
    int R = bid*16 + r;
    int rl = R & 15, gate = rl >> 2, jj = rl & 3;
    int grow = gate*1024 + bid*4 + jj;
    int k0 = (kq*NIT + it)*32 + q*8;
    u16 hv[8], lv[8];
    #pragma unroll
    for (int e=0; e<8; ++e){
      int k = k0 + e;
      float v = 0.f;
      if (k < Kih)      v = wih[(size_t)grow*Kih + k];
      else if (k < Kin) v = whh[(size_t)grow*HH + (k - Kih)];
      u16 h = f2bf(v);
      hv[e] = h;
      lv[e] = f2bf(v - bf2f(h));
    }
    *(ulonglong2*)(wh + E*8) = *(ulonglong2*)hv;
    *(ulonglong2*)(wl + E*8) = *(ulonglong2*)lv;
  }
}

__global__ __launch_bounds__(256) void bsum_kernel(
    const float* __restrict__ bih1, const float* __restrict__ bhh1,
    const float* __restrict__ bih2, const float* __restrict__ bhh2,
    const float* __restrict__ bih3, const float* __restrict__ bhh3,
    float* __restrict__ bs0, float* __restrict__ bs1, float* __restrict__ bs2){
  int idx = blockIdx.x*256 + threadIdx.x;
  if (idx < 4096)       bs0[idx] = bih1[idx] + bhh1[idx];
  else if (idx < 8192){ int r=idx-4096; bs1[r] = bih2[r] + bhh2[r]; }
  else if (idx < 12288){int r=idx-8192; bs2[r] = bih3[r] + bhh3[r]; }
}

__global__ void barinit_kernel(u32* bar){
  for (int i = threadIdx.x; i < 512; i += 256) bar[i] = 0u;
}

// ---------------------------------------------------------------------------
struct SeqArgs {
  const float *x;
  const float *wa[3];
  const float *wout, *bout;
  const u16 *enc;
  const u16 *wwh[3], *wwl[3];
  const float *bsum[3];
  u16 *pl[3][2][2];            // fragment-major x planes
  float *hbuf;
  float *cbuf;
  float *dout;
  u32 *slots;
  u32 *go;
};

#define SMEM_FLOATS 5376

// fence-free distributed-slot grid barrier (R8 proven)
__device__ __forceinline__ void gbar(const SeqArgs& A, u32 nb){
  asm volatile("s_waitcnt vmcnt(0)" ::: "memory");
  __syncthreads();
  const int bid = blockIdx.x, tid = threadIdx.x;
  if (tid == 0)
    __hip_atomic_store(A.slots + bid, nb, __ATOMIC_RELEASE,
                       __HIP_MEMORY_SCOPE_AGENT);
  if (bid == 0){
    if (tid < 64){
      for (;;){
        u32 v0 = lda32u(A.slots + tid);
        u32 v1 = lda32u(A.slots + 64 + tid);
        u32 v2 = lda32u(A.slots + 128 + tid);
        u32 v3 = lda32u(A.slots + 192 + tid);
        u32 mn = min(min(v0,v1), min(v2,v3));
        if (__all(mn >= nb)) break;
        __builtin_amdgcn_s_sleep(4);
      }
      if (tid == 0) sta32(A.go, nb);
    }
  } else if (tid == 0){
    while (lda32u(A.go) < nb) __builtin_amdgcn_s_sleep(4);
  }
  __syncthreads();
}

// attend for (l,b) parity par: q = wa^T h ; softmax(enc.q) ; ctx -> plane
__device__ void attend_phase(const SeqArgs& A, int l, int par, int b, float* sm){
  const int tid = threadIdx.x;
  const float* wa = A.wa[l];
  const float* h  = A.hbuf + (size_t)((l*2+par)*BB + b)*HH;
  const int NITl = (l==0)? NIT0 : NIT12;
  u16* ch = A.pl[l][par][0];
  u16* cl = A.pl[l][par][1];
  float* sh  = sm;
  float* sq  = sm + 1024;
  float* ss  = sm + 1056;
  float* red = sm + 3104;
  float* ctxf= sm + 4128;

  sh[tid] = lda32f(h + tid);
  __syncthreads();

  const int cc = tid&31, g = tid>>5;
  float part = 0.f;
  for (int kk=g; kk<HH; kk+=32) part += wa[kk*32+cc]*sh[kk];
  red[tid] = part; __syncthreads();
  if (tid<32){ float s=0.f;
    #pragma unroll
    for (int gg=0; gg<32; ++gg) s += red[gg*32+tid];
    sq[tid]=s; }
  __syncthreads();

  const u16* eb = A.enc + (size_t)b*LL3*CC3;
  float lmax = -1e30f;
  for (int t=tid; t<LL3; t+=1024){
    const u16* er = eb + t*32; float dot=0.f;
    #pragma unroll
    for (int c4=0;c4<8;++c4){
      u64 w = *(const u64*)(er + c4*4);
      dot += bfq(w,0)*sq[c4*4] + bfq(w,1)*sq[c4*4+1]
           + bfq(w,2)*sq[c4*4+2] + bfq(w,3)*sq[c4*4+3];
    }
    ss[t]=dot; lmax=fmaxf(lmax,dot);
  }
  #pragma unroll
  for (int o=32;o>0;o>>=1) lmax = fmaxf(lmax, __shfl_xor(lmax,o));
  if ((tid&63)==0) red[tid>>6] = lmax;
  __syncthreads();
  if (tid==0){ float m=red[0]; for (int w=1;w<16;++w) m=fmaxf(m,red[w]); red[16]=m; }
  __syncthreads();
  const float m = red[16];

  float lsum = 0.f;
  for (int t=tid; t<LL3; t+=1024){ float e=__expf(ss[t]-m); ss[t]=e; lsum+=e; }
  #pragma unroll
  for (int o=32;o>0;o>>=1) lsum += __shfl_xor(lsum,o);
  if ((tid&63)==0) red[32 + (tid>>6)] = lsum;
  __syncthreads();
  if (tid==0){ float z=0.f; for (int w=0;w<16;++w) z+=red[32+w]; red[17]=1.0f/z; }
  __syncthreads();
  const float rZ = red[17];

  float acc = 0.f;
  for (int t=g; t<LL3; t+=32) acc += ss[t]*bf2f(eb[t*32+cc]);
  __syncthreads();
  red[tid] = acc; __syncthreads();
  if (tid<32){ float s=0.f;
    #pragma unroll
    for (int gg=0; gg<32; ++gg) s += red[gg*32+tid];
    ctxf[tid] = s*rZ; }
  __syncthreads();
  if (tid < 16){
    float v0=ctxf[2*tid], v1=ctxf[2*tid+1];
    sta32((u32*)ch + xidx(NITl, b, 2*tid), (u32)f2bf(v0) | ((u32)f2bf(v1)<<16));
  } else if (tid < 32){
    int t2 = tid-16;
    float v0=ctxf[2*t2], v1=ctxf[2*t2+1];
    u16 h0=f2bf(v0), h1=f2bf(v1);
    sta32((u32*)cl + xidx(NITl, b, 2*t2),
          (u32)f2bf(v0-bf2f(h0)) | ((u32)f2bf(v1-bf2f(h1))<<16));
  }
}

// out phase: y(s) -> dout[:,s,:]; y -> prev slot (k=32..96) of l0 plane pn.
__device__ void out_phase(const SeqArgs& A, int pn, int s, int b, float* sm){
  float* sh = sm; float* red = sm+1024; float* yv = sm+2048;
  const int tid = threadIdx.x;
  sh[tid] = lda32f(A.hbuf + (size_t)((2*2+pn)*BB + b)*HH + tid);
  __syncthreads();
  const int d = tid&63, kg = tid>>6;
  const float* wr = A.wout + (size_t)d*HH + kg*64;
  const float* hh = sh + kg*64;
  float acc = 0.f;
  #pragma unroll
  for (int k=0;k<64;k+=4){ float4 w4=ld4(wr+k); float4 hv=*(const float4*)&hh[k];
    acc += w4.x*hv.x+w4.y*hv.y+w4.z*hv.z+w4.w*hv.w; }
  red[tid]=acc; __syncthreads();
  if (tid<64){
    float y = A.bout[tid];
    #pragma unroll
    for (int kk=0;kk<16;++kk) y += red[kk*64+tid];
    A.dout[((size_t)b*NSTEP+s)*DOUT+tid] = y;
    yv[tid] = y;
  }
  __syncthreads();
  if (tid < 32){
    float v0=yv[2*tid], v1=yv[2*tid+1];
    sta32((u32*)A.pl[0][pn][0] + xidx(NIT0, b, 32 + 2*tid),
          (u32)f2bf(v0) | ((u32)f2bf(v1)<<16));
  } else if (tid < 64){
    int t2 = tid-32;
    float v0=yv[2*t2], v1=yv[2*t2+1];
    u16 h0=f2bf(v0), h1=f2bf(v1);
    sta32((u32*)A.pl[0][pn][1] + xidx(NIT0, b, 32 + 2*t2),
          (u32)f2bf(v0-bf2f(h0)) | ((u32)f2bf(v1-bf2f(h1))<<16));
  }
}

// MFMA GEMM (16 weight rows x 32 batch per block, 256 blocks) + fused cell.
// waves = xh(2) x kq(8); per-wave contiguous 1KB/iter streams.
template<int L, int NIT>
__device__ void gemm_phase(const SeqArgs& A, int p, int pn, float* sm){
  const int bid = blockIdx.x, tid = threadIdx.x;
  const u16* wh  = A.wwh[L];
  const u16* wlo = A.wwl[L];
  const u16* ih = A.pl[L][p][0];
  const u16* il = A.pl[L][p][1];
  const int wave = tid>>6, lane = tid&63;
  const int xh = wave>>3, kq = wave&7;
  const size_t wbase = (((size_t)bid*8 + kq)*NIT)*512 + lane*8;
  const size_t xbase = (((size_t)xh*8 + kq)*NIT)*512 + lane*8;
  const u16* wph = wh  + wbase;
  const u16* wpl = wlo + wbase;
  const u16* xb  = ih + xbase;
  const u16* xlb = il + xbase;

  f32x4 acc0 = {0.f,0.f,0.f,0.f}, acc1 = {0.f,0.f,0.f,0.f}, acc2 = {0.f,0.f,0.f,0.f};
  bf16x8 whA, wlA, whB, wlB;
  FR xhA, xlA, xhB, xlB;
  whA = *(const bf16x8*)(wph);
  wlA = *(const bf16x8*)(wpl);
  xhA.q[0] = lda64(xb);    xhA.q[1] = lda64(xb+4);
  xlA.q[0] = lda64(xlb);   xlA.q[1] = lda64(xlb+4);
  #pragma unroll
  for (int it = 0; it < NIT; ++it){
    const int o = (it+1)*512;
    if ((it & 1) == 0){
      if (it+1 < NIT){
        whB = *(const bf16x8*)(wph + o);
        wlB = *(const bf16x8*)(wpl + o);
        xhB.q[0] = lda64(xb+o);  xhB.q[1] = lda64(xb+o+4);
        xlB.q[0] = lda64(xlb+o); xlB.q[1] = lda64(xlb+o+4);
      }
      acc0 = __builtin_amdgcn_mfma_f32_16x16x32_bf16(xhA.v, whA, acc0, 0,0,0);
      acc1 = __builtin_amdgcn_mfma_f32_16x16x32_bf16(xlA.v, whA, acc1, 0,0,0);
      acc2 = __builtin_amdgcn_mfma_f32_16x16x32_bf16(xhA.v, wlA, acc2, 0,0,0);
    } else {
      if (it+1 < NIT){
        whA = *(const bf16x8*)(wph + o);
        wlA = *(const bf16x8*)(wpl + o);
        xhA.q[0] = lda64(xb+o);  xhA.q[1] = lda64(xb+o+4);
        xlA.q[0] = lda64(xlb+o); xlA.q[1] = lda64(xlb+o+4);
      }
      acc0 = __builtin_amdgcn_mfma_f32_16x16x32_bf16(xhB.v, whB, acc0, 0,0,0);
      acc1 = __builtin_amdgcn_mfma_f32_16x16x32_bf16(xlB.v, whB, acc1, 0,0,0);
      acc2 = __builtin_amdgcn_mfma_f32_16x16x32_bf16(xhB.v, wlB, acc2, 0,0,0);
    }
  }
  f32x4 acc = acc0 + acc1 + acc2;

  float* red = sm;            // 16*256
  float* sg  = sm + 4096;     // 16*32
  float* hv  = sm + 4608;     // 4*32
  #pragma unroll
  for (int rg=0; rg<4; ++rg) red[wave*256 + lane*4 + rg] = acc[rg];
  __syncthreads();
  if (tid < 512){
    const int xh2 = tid>>8, e = tid&255;
    float v = 0.f;
    #pragma unroll
    for (int k2=0; k2<8; ++k2) v += red[(xh2*8 + k2)*256 + e];
    const int ln = e>>2, rg = e&3;
    // D layout (m89): col=lane&15 -> weight row, row=4*(lane>>4)+reg -> batch
    sg[(ln&15)*32 + xh2*16 + ((ln>>4)<<2) + rg] = v;
  }
  __syncthreads();
  if (tid < 128){
    const int b = tid&31, jj = tid>>5;        // jj = 0..3
    const int j = bid*4 + jj;
    const float* bs = A.bsum[L];
    float gi = sg[(0 +jj)*32+b] + bs[j];
    float gf = sg[(4 +jj)*32+b] + bs[1024+j];
    float gg = sg[(8 +jj)*32+b] + bs[2048+j];
    float go = sg[(12+jj)*32+b] + bs[3072+j];
    float i_ = 1.f/(1.f+__expf(-gi));
    float f_ = 1.f/(1.f+__expf(-gf));
    float g_ = tanhf(gg);
    float o_ = 1.f/(1.f+__expf(-go));
    float* cb = A.cbuf + ((size_t)L*BB + b)*HH + j;
    float c = f_*cb[0] + i_*g_;
    cb[0] = c;
    float hval = o_*tanhf(c);
    sta32f(A.hbuf + ((size_t)(L*2+pn)*BB + b)*HH + j, hval);
    hv[jj*32 + b] = hval;
  }
  __syncthreads();
  if (tid < 64){
    const int b = tid&31, pr = tid>>5;        // pr = 0..1
    const int jj0 = pr*2;
    float v0 = hv[jj0*32+b], v1 = hv[(jj0+1)*32+b];
    u16 h0 = f2bf(v0), h1 = f2bf(v1);
    u32 ph  = (u32)h0 | ((u32)h1<<16);
    u32 plq = (u32)f2bf(v0-bf2f(h0)) | ((u32)f2bf(v1-bf2f(h1))<<16);
    const int col = bid*4 + jj0;
    if (L == 0){
      u32 i1 = xidx(NIT0,  b, 96 + col);     // own h1, next step
      sta32((u32*)A.pl[0][pn][0] + i1, ph);  sta32((u32*)A.pl[0][pn][1] + i1, plq);
      u32 i2 = xidx(NIT12, b, 32 + col);     // L2 input, this step
      sta32((u32*)A.pl[1][p ][0] + i2, ph);  sta32((u32*)A.pl[1][p ][1] + i2, plq);
    } else if (L == 1){
      u32 i1 = xidx(NIT12, b, 1056 + col);   // own h2, next step
      sta32((u32*)A.pl[1][pn][0] + i1, ph);  sta32((u32*)A.pl[1][pn][1] + i1, plq);
      u32 i2 = xidx(NIT12, b, 32 + col);     // L3 input, this step
      sta32((u32*)A.pl[2][p ][0] + i2, ph);  sta32((u32*)A.pl[2][p ][1] + i2, plq);
    } else {
      u32 i1 = xidx(NIT12, b, 1056 + col);   // own h3, next step
      sta32((u32*)A.pl[2][pn][0] + i1, ph);  sta32((u32*)A.pl[2][pn][1] + i1, plq);
    }
  }
}

__global__ __launch_bounds__(1024, 4) void seq_kernel(SeqArgs A){
  __shared__ float sm[SMEM_FLOATS];
  const int bid = blockIdx.x, tid = threadIdx.x;
  const size_t gid = (size_t)bid*1024 + tid;
  const size_t gstr = (size_t)256*1024;
  u32 nb = 0;

  // ---- init: zero ALL planes (incl pads), hbuf par0, cbuf ----
  {
    const size_t n0 = (size_t)32*(KP0>>1);      // u32 per l0 buffer
    const size_t n1 = (size_t)32*(KP12>>1);     // u32 per l1/l2 buffer
    for (size_t i = gid; i < n0; i += gstr){
      #pragma unroll
      for (int q=0;q<2;++q)
        #pragma unroll
        for (int hl=0;hl<2;++hl)
          sta32((u32*)A.pl[0][q][hl] + i, 0u);
    }
    for (size_t i = gid; i < n1; i += gstr){
      #pragma unroll
      for (int q=0;q<2;++q)
        #pragma unroll
        for (int hl=0;hl<2;++hl){
          sta32((u32*)A.pl[1][q][hl] + i, 0u);
          sta32((u32*)A.pl[2][q][hl] + i, 0u);
        }
    }
  }
  for (size_t i = gid; i < (size_t)3*32*1024; i += gstr){
    size_t l2 = i >> 15, r = i & 32767, b = r >> 10, j = r & 1023;
    sta32f(A.hbuf + ((l2*2+0)*BB + b)*HH + j, 0.f);
  }
  {
    for (int t = tid; t < 3*32*4; t += 1024){
      int l2 = t>>7, r = t&127, b = r>>2, jj = r&3;
      A.cbuf[((size_t)l2*BB + b)*HH + bid*4 + jj] = 0.f;
    }
  }
  gbar(A, ++nb);

  // P0: att1/2/3(0) at parity 0 ; prev(0) = x[:,T-1,:] into l0 plane par0.
  if (bid >= 128 && bid < 224){
    int l = (bid-128)>>5, b = (bid-128)&31;
    attend_phase(A, l, 0, b, sm);
  } else if (bid >= 224){
    int b = bid - 224;
    if (tid < 64 && (tid & 1) == 0){
      float v  = A.x[((size_t)b*TT + (TT-1))*DIN + tid];
      float v1 = A.x[((size_t)b*TT + (TT-1))*DIN + tid + 1];
      u16 h = f2bf(v), h1 = f2bf(v1);
      u32 idx = xidx(NIT0, b, 32 + tid);
      sta32((u32*)A.pl[0][0][0] + idx, (u32)h | ((u32)h1<<16));
      u16 l0 = f2bf(v - bf2f(h)), l1 = f2bf(v1 - bf2f(h1));
      sta32((u32*)A.pl[0][0][1] + idx, (u32)l0 | ((u32)l1<<16));
    }
  }
  gbar(A, ++nb);

  for (int s = 0; s < NSTEP; ++s){
    const int p = s&1, pn = p^1;
    // P1: G1(s) on ALL 256 blocks
    gemm_phase<0,NIT0>(A, p, pn, sm);
    gbar(A, ++nb);
    // P2: G2(s) on ALL 256 blocks
    gemm_phase<1,NIT12>(A, p, pn, sm);
    gbar(A, ++nb);
    // P3: G3(s) on ALL 256 blocks
    gemm_phase<2,NIT12>(A, p, pn, sm);
    gbar(A, ++nb);
    // P4: att1/att2/att3(s+1) + out(s) on 128 blocks
    if (bid >= 128 && bid < 224){
      int l = (bid-128)>>5, b = (bid-128)&31;
      attend_phase(A, l, pn, b, sm);
    } else if (bid >= 224){
      out_phase(A, pn, s, bid-224, sm);
    }
    gbar(A, ++nb);
  }
}

// ---------------------------------------------------------------------------
extern "C" void kernel_launch(void* const* d_in, const int* in_sizes, int n_in,
                              void* d_out, int out_size, void* d_ws, size_t ws_size,
                              hipStream_t stream) {
  const float* x    = (const float*)d_in[0];
  const float* w_c1 = (const float*)d_in[1];
  const float* b_c1 = (const float*)d_in[2];
  const float* w_c2 = (const float*)d_in[3];
  const float* b_c2 = (const float*)d_in[4];
  const float* w_c3 = (const float*)d_in[5];
  const float* b_c3 = (const float*)d_in[6];

  SeqArgs A;
  A.x     = x;
  A.wa[0] = (const float*)d_in[7];
  A.wa[1] = (const float*)d_in[9];
  A.wa[2] = (const float*)d_in[11];
  const float* wih1 = (const float*)d_in[13];
  const float* whh1 = (const float*)d_in[14];
  const float* bih1 = (const float*)d_in[15];
  const float* bhh1 = (const float*)d_in[16];
  const float* wih2 = (const float*)d_in[17];
  const float* whh2 = (const float*)d_in[18];
  const float* bih2 = (const float*)d_in[19];
  const float* bhh2 = (const float*)d_in[20];
  const float* wih3 = (const float*)d_in[21];
  const float* whh3 = (const float*)d_in[22];
  const float* bih3 = (const float*)d_in[23];
  const float* bhh3 = (const float*)d_in[24];
  A.wout = (const float*)d_in[25];
  A.bout = (const float*)d_in[26];
  A.dout = (float*)d_out;

  char* base = (char*)d_ws;
  size_t off = 0;
  auto alloc = [&](size_t bytes)->char*{
    char* pp = base + off; off = (off + bytes + 255) & ~(size_t)255; return pp;
  };

  u16* enc = (u16*)alloc((size_t)BB*LL3*CC3*2);
  A.enc  = enc;
  A.hbuf = (float*)alloc((size_t)3*2*BB*HH*4);
  A.cbuf = (float*)alloc((size_t)3*BB*HH*4);
  for (int l=0;l<3;++l){
    size_t kp = (l==0)? KP0 : KP12;
    for (int par=0; par<2; ++par)
      for (int hl=0; hl<2; ++hl)
        A.pl[l][par][hl] = (u16*)alloc((size_t)BB*kp*2);
  }
  float* bs0 = (float*)alloc(4096*4);
  float* bs1 = (float*)alloc(4096*4);
  float* bs2 = (float*)alloc(4096*4);
  A.bsum[0]=bs0; A.bsum[1]=bs1; A.bsum[2]=bs2;
  u32* bar = (u32*)alloc(4096);
  A.slots = bar;
  A.go    = bar + 320;
  u16 *wp[6];
  wp[0] = (u16*)alloc((size_t)4096*KP0*2);     // 256*8*NIT0*512 u16 = 4096*1280
  wp[1] = (u16*)alloc((size_t)4096*KP0*2);
  wp[2] = (u16*)alloc((size_t)4096*KP12*2);    // 4096*2304
  wp[3] = (u16*)alloc((size_t)4096*KP12*2);
  wp[4] = (u16*)alloc((size_t)4096*KP12*2);
  wp[5] = (u16*)alloc((size_t)4096*KP12*2);
  A.wwh[0]=wp[0]; A.wwl[0]=wp[1];
  A.wwh[1]=wp[2]; A.wwl[1]=wp[3];
  A.wwh[2]=wp[4]; A.wwl[2]=wp[5];

  // conv temps alias the layer-1 hi weight buffer (preps run after convs)
  float* r1 = (float*)wp[0];                         // 2.09 MB
  float* r2 = (float*)(((char*)wp[0]) + 2095104);    // 4.17 MB (< 10.4 MB)

  conv1_kernel<<<(BB*LL1+255)/256, 256, 0, stream>>>(x, w_c1, b_c1, r1);
  conv2_kernel<<<(BB*LL2+255)/256, 256, 0, stream>>>(r1, w_c2, b_c2, r2);
  conv3_kernel<<<(BB*LL3+255)/256, 256, 0, stream>>>(r2, w_c3, b_c3, enc);
  prep_kernel<<<2048, 256, 0, stream>>>(wih1, whh1, wp[0], wp[1],   96, K0,  NIT0);
  prep_kernel<<<2048, 256, 0, stream>>>(wih2, whh2, wp[2], wp[3], 1056, K12, NIT12);
  prep_kernel<<<2048, 256, 0, stream>>>(wih3, whh3, wp[4], wp[5], 1056, K12, NIT12);
  bsum_kernel<<<48, 256, 0, stream>>>(bih1,bhh1,bih2,bhh2,bih3,bhh3, bs0,bs1,bs2);
  barinit_kernel<<<1, 256, 0, stream>>>(bar);

  void* params[] = { (void*)&A };
  hipLaunchCooperativeKernel((const void*)seq_kernel, dim3(256), dim3(1024),
                             params, 0, stream);
}

// Round 12
// 3643.553 us; speedup vs baseline: 2.4413x; 1.3503x over previous
//
#include <hip/hip_runtime.h>

// ============================================================================
// Conv2Seq round 11: R10 + SINGLE-bf16 GEMM (drop hi/lo correction streams).
// R10 PMC: pinned at per-CU far-memory BW (~19-26 GB/s/CU, MSHR-limited),
// all 256 CUs active -> only lever is fewer bytes. Corrections (wl,xl) were
// half the stream and guard precision ~2^-18, invisible under the 2^-10
// comparison floor (absmax bit-identical across fp32 R1 and split R5-R10).
// Now: 2KB/wave-iter (wh 1KB + xh 1KB), 1 MFMA/iter. Rest = R10 verbatim.
// ============================================================================

#define BB   32
#define TT   2048
#define DIN  64
#define HH   1024
#define DOUT 64
#define NSTEP 60
#define LL1  2045
#define LL2  2038
#define LL3  2023
#define CC1  8
#define CC2  16
#define CC3  32
#define K0   1120
#define K12  2080
#define KP0  1280     // 8 kq * NIT0(5) * 32
#define KP12 2304     // 8 kq * NIT12(9) * 32
#define NIT0  5
#define NIT12 9

typedef unsigned short u16;
typedef unsigned int   u32;
typedef unsigned long long u64;
typedef __attribute__((ext_vector_type(8))) short bf16x8;
typedef __attribute__((ext_vector_type(4))) float f32x4;

union FR { u64 q[2]; bf16x8 v; };

__device__ __forceinline__ float4 ld4(const float* p){ return *(const float4*)p; }
__device__ __forceinline__ u16 f2bf(float x){
  unsigned u = __float_as_uint(x);
  return (u16)((u + 0x7FFFu + ((u>>16)&1u)) >> 16);
}
__device__ __forceinline__ float bf2f(u16 h){ return __uint_as_float(((unsigned)h)<<16); }
__device__ __forceinline__ float bfq(u64 w, int i){
  return __uint_as_float(((u32)((w >> (16*i)) & 0xffffu)) << 16);
}
// coherent-point accessors (bypass stale L1/L2) for cross-block mutable data
__device__ __forceinline__ float lda32f(const float* p){
  return __hip_atomic_load(p, __ATOMIC_RELAXED, __HIP_MEMORY_SCOPE_AGENT);
}
__device__ __forceinline__ u32 lda32u(const u32* p){
  return __hip_atomic_load(p, __ATOMIC_RELAXED, __HIP_MEMORY_SCOPE_AGENT);
}
__device__ __forceinline__ u64 lda64(const void* p){
  return __hip_atomic_load((const u64*)p, __ATOMIC_RELAXED, __HIP_MEMORY_SCOPE_AGENT);
}
__device__ __forceinline__ void sta32(u32* p, u32 v){
  __hip_atomic_store(p, v, __ATOMIC_RELAXED, __HIP_MEMORY_SCOPE_AGENT);
}
__device__ __forceinline__ void sta32f(float* p, float v){
  __hip_atomic_store(p, v, __ATOMIC_RELAXED, __HIP_MEMORY_SCOPE_AGENT);
}

// u32 slot index of pair (b, k) [k even] in a fragment-major x plane.
// entry = ((xh*8 + kq)*NIT + it)*64 + q*16 + r ; 4 u32 per entry.
// k = (kq*NIT + it)*32 + q*8 + e
__device__ __forceinline__ u32 xidx(int NIT, int b, int k){
  int r = b & 15, xh = b >> 4;
  int c = k >> 5;
  int kq = c / NIT, it = c - kq*NIT;
  int q = (k >> 3) & 3, e = k & 7;
  return (u32)((((xh*8 + kq)*NIT + it)*64 + q*16 + r)*4 + (e >> 1));
}

// ---------------------------------------------------------------------------
// conv kernels (one-shot; conv3 emits bf16 enc)
// ---------------------------------------------------------------------------
__global__ __launch_bounds__(256) void conv1_kernel(const float* __restrict__ x,
    const float* __restrict__ w, const float* __restrict__ bias,
    float* __restrict__ out){
  int idx = blockIdx.x*256 + threadIdx.x;
  if (idx >= BB*LL1) return;
  int b = idx / LL1, t = idx % LL1;
  float acc[CC1];
  #pragma unroll
  for (int c=0;c<CC1;++c) acc[c] = bias[c];
  for (int k=0;k<4;++k){
    const float* xr = x + ((size_t)(b*TT + t + k))*DIN;
    for (int d=0; d<DIN; d+=4){
      float4 v = ld4(xr + d);
      #pragma unroll
      for (int c=0;c<CC1;++c){
        acc[c] += v.x * w[((c*DIN+d  )<<2)+k]
                + v.y * w[((c*DIN+d+1)<<2)+k]
                + v.z * w[((c*DIN+d+2)<<2)+k]
                + v.w * w[((c*DIN+d+3)<<2)+k];
      }
    }
  }
  float* o = out + (size_t)idx*CC1;
  #pragma unroll
  for (int c=0;c<CC1;++c) o[c] = fmaxf(acc[c], 0.f);
}

__global__ __launch_bounds__(256) void conv2_kernel(const float* __restrict__ r1,
    const float* __restrict__ w, const float* __restrict__ bias,
    float* __restrict__ out){
  int idx = blockIdx.x*256 + threadIdx.x;
  if (idx >= BB*LL2) return;
  int b = idx / LL2, t = idx % LL2;
  float acc[CC2];
  #pragma unroll
  for (int c=0;c<CC2;++c) acc[c] = bias[c];
  for (int k=0;k<8;++k){
    const float* rr = r1 + ((size_t)(b*LL1 + t + k))*CC1;
    for (int c1=0;c1<CC1;c1+=4){
      float4 v = ld4(rr + c1);
      #pragma unroll
      for (int c=0;c<CC2;++c){
        acc[c] += v.x * w[((c*CC1+c1  )<<3)+k]
                + v.y * w[((c*CC1+c1+1)<<3)+k]
                + v.z * w[((c*CC1+c1+2)<<3)+k]
                + v.w * w[((c*CC1+c1+3)<<3)+k];
      }
    }
  }
  float* o = out + (size_t)idx*CC2;
  #pragma unroll
  for (int c=0;c<CC2;++c) o[c] = fmaxf(acc[c], 0.f);
}

__global__ __launch_bounds__(256) void conv3_kernel(const float* __restrict__ r2,
    const float* __restrict__ w, const float* __restrict__ bias,
    u16* __restrict__ out){
  int idx = blockIdx.x*256 + threadIdx.x;
  if (idx >= BB*LL3) return;
  int b = idx / LL3, t = idx % LL3;
  float acc[CC3];
  #pragma unroll
  for (int c=0;c<CC3;++c) acc[c] = bias[c];
  for (int k=0;k<16;++k){
    const float* rr = r2 + ((size_t)(b*LL2 + t + k))*CC2;
    for (int c2=0;c2<CC2;c2+=4){
      float4 v = ld4(rr + c2);
      #pragma unroll
      for (int c=0;c<CC3;++c){
        acc[c] += v.x * w[((c*CC2+c2  )<<4)+k]
                + v.y * w[((c*CC2+c2+1)<<4)+k]
                + v.z * w[((c*CC2+c2+2)<<4)+k]
                + v.w * w[((c*CC2+c2+3)<<4)+k];
      }
    }
  }
  u16* o = out + (size_t)idx*CC3;
  #pragma unroll
  for (int c=0;c<CC3;++c) o[c] = f2bf(fmaxf(acc[c], 0.f));
}

// ---------------------------------------------------------------------------
// weight prep, FRAGMENT-MAJOR for 16-row blocks (bf16 only, no lo plane):
// E = ((bid*8 + kq)*NIT + it)*64 + lane; lane = q*16 + r.
// row R = bid*16 + r; rl = R&15; gate = rl>>2; jj = rl&3;
// grow = gate*1024 + bid*4 + jj; k = (kq*NIT+it)*32 + q*8 + e.
// ---------------------------------------------------------------------------
__global__ __launch_bounds__(256) void prep_kernel(const float* __restrict__ wih,
    const float* __restrict__ whh, u16* __restrict__ wh,
    int Kih, int Kin, int NIT){
  const size_t total = (size_t)256*8*NIT*64;
  for (size_t E = (size_t)blockIdx.x*256 + threadIdx.x; E < total;
       E += (size_t)gridDim.x*256){
    int lane = (int)(E & 63);
    size_t t1 = E >> 6;
    int it = (int)(t1 % NIT);  t1 /= NIT;
    int kq = (int)(t1 & 7);    int bid = (int)(t1 >> 3);
    int r = lane & 15, q = lane >> 4;
    int R = bid*16 + r;
    int rl = R & 15, gate = rl >> 2, jj = rl & 3;
    int grow = gate*1024 + bid*4 + jj;
    int k0 = (kq*NIT + it)*32 + q*8;
    u16 hv[8];
    #pragma unroll
    for (int e=0; e<8; ++e){
      int k = k0 + e;
      float v = 0.f;
      if (k < Kih)      v = wih[(size_t)grow*Kih + k];
      else if (k < Kin) v = whh[(size_t)grow*HH + (k - Kih)];
      hv[e] = f2bf(v);
    }
    *(ulonglong2*)(wh + E*8) = *(ulonglong2*)hv;
  }
}

__global__ __launch_bounds__(256) void bsum_kernel(
    const float* __restrict__ bih1, const float* __restrict__ bhh1,
    const float* __restrict__ bih2, const float* __restrict__ bhh2,
    const float* __restrict__ bih3, const float* __restrict__ bhh3,
    float* __restrict__ bs0, float* __restrict__ bs1, float* __restrict__ bs2){
  int idx = blockIdx.x*256 + threadIdx.x;
  if (idx < 4096)       bs0[idx] = bih1[idx] + bhh1[idx];
  else if (idx < 8192){ int r=idx-4096; bs1[r] = bih2[r] + bhh2[r]; }
  else if (idx < 12288){int r=idx-8192; bs2[r] = bih3[r] + bhh3[r]; }
}

__global__ void barinit_kernel(u32* bar){
  for (int i = threadIdx.x; i < 512; i += 256) bar[i] = 0u;
}

// ---------------------------------------------------------------------------
struct SeqArgs {
  const float *x;
  const float *wa[3];
  const float *wout, *bout;
  const u16 *enc;
  const u16 *wwh[3];
  const float *bsum[3];
  u16 *pl[3][2];               // fragment-major x planes [layer][parity]
  float *hbuf;
  float *cbuf;
  float *dout;
  u32 *slots;
  u32 *go;
};

#define SMEM_FLOATS 5376

// fence-free distributed-slot grid barrier (R8/R10 proven)
__device__ __forceinline__ void gbar(const SeqArgs& A, u32 nb){
  asm volatile("s_waitcnt vmcnt(0)" ::: "memory");
  __syncthreads();
  const int bid = blockIdx.x, tid = threadIdx.x;
  if (tid == 0)
    __hip_atomic_store(A.slots + bid, nb, __ATOMIC_RELEASE,
                       __HIP_MEMORY_SCOPE_AGENT);
  if (bid == 0){
    if (tid < 64){
      for (;;){
        u32 v0 = lda32u(A.slots + tid);
        u32 v1 = lda32u(A.slots + 64 + tid);
        u32 v2 = lda32u(A.slots + 128 + tid);
        u32 v3 = lda32u(A.slots + 192 + tid);
        u32 mn = min(min(v0,v1), min(v2,v3));
        if (__all(mn >= nb)) break;
        __builtin_amdgcn_s_sleep(4);
      }
      if (tid == 0) sta32(A.go, nb);
    }
  } else if (tid == 0){
    while (lda32u(A.go) < nb) __builtin_amdgcn_s_sleep(4);
  }
  __syncthreads();
}

// attend for (l,b) parity par: q = wa^T h ; softmax(enc.q) ; ctx -> plane
__device__ void attend_phase(const SeqArgs& A, int l, int par, int b, float* sm){
  const int tid = threadIdx.x;
  const float* wa = A.wa[l];
  const float* h  = A.hbuf + (size_t)((l*2+par)*BB + b)*HH;
  const int NITl = (l==0)? NIT0 : NIT12;
  u16* ch = A.pl[l][par];
  float* sh  = sm;
  float* sq  = sm + 1024;
  float* ss  = sm + 1056;
  float* red = sm + 3104;
  float* ctxf= sm + 4128;

  sh[tid] = lda32f(h + tid);
  __syncthreads();

  const int cc = tid&31, g = tid>>5;
  float part = 0.f;
  for (int kk=g; kk<HH; kk+=32) part += wa[kk*32+cc]*sh[kk];
  red[tid] = part; __syncthreads();
  if (tid<32){ float s=0.f;
    #pragma unroll
    for (int gg=0; gg<32; ++gg) s += red[gg*32+tid];
    sq[tid]=s; }
  __syncthreads();

  const u16* eb = A.enc + (size_t)b*LL3*CC3;
  float lmax = -1e30f;
  for (int t=tid; t<LL3; t+=1024){
    const u16* er = eb + t*32; float dot=0.f;
    #pragma unroll
    for (int c4=0;c4<8;++c4){
      u64 w = *(const u64*)(er + c4*4);
      dot += bfq(w,0)*sq[c4*4] + bfq(w,1)*sq[c4*4+1]
           + bfq(w,2)*sq[c4*4+2] + bfq(w,3)*sq[c4*4+3];
    }
    ss[t]=dot; lmax=fmaxf(lmax,dot);
  }
  #pragma unroll
  for (int o=32;o>0;o>>=1) lmax = fmaxf(lmax, __shfl_xor(lmax,o));
  if ((tid&63)==0) red[tid>>6] = lmax;
  __syncthreads();
  if (tid==0){ float m=red[0]; for (int w=1;w<16;++w) m=fmaxf(m,red[w]); red[16]=m; }
  __syncthreads();
  const float m = red[16];

  float lsum = 0.f;
  for (int t=tid; t<LL3; t+=1024){ float e=__expf(ss[t]-m); ss[t]=e; lsum+=e; }
  #pragma unroll
  for (int o=32;o>0;o>>=1) lsum += __shfl_xor(lsum,o);
  if ((tid&63)==0) red[32 + (tid>>6)] = lsum;
  __syncthreads();
  if (tid==0){ float z=0.f; for (int w=0;w<16;++w) z+=red[32+w]; red[17]=1.0f/z; }
  __syncthreads();
  const float rZ = red[17];

  float acc = 0.f;
  for (int t=g; t<LL3; t+=32) acc += ss[t]*bf2f(eb[t*32+cc]);
  __syncthreads();
  red[tid] = acc; __syncthreads();
  if (tid<32){ float s=0.f;
    #pragma unroll
    for (int gg=0; gg<32; ++gg) s += red[gg*32+tid];
    ctxf[tid] = s*rZ; }
  __syncthreads();
  if (tid < 16){
    float v0=ctxf[2*tid], v1=ctxf[2*tid+1];
    sta32((u32*)ch + xidx(NITl, b, 2*tid), (u32)f2bf(v0) | ((u32)f2bf(v1)<<16));
  }
}

// out phase: y(s) -> dout[:,s,:]; y -> prev slot (k=32..96) of l0 plane pn.
__device__ void out_phase(const SeqArgs& A, int pn, int s, int b, float* sm){
  float* sh = sm; float* red = sm+1024; float* yv = sm+2048;
  const int tid = threadIdx.x;
  sh[tid] = lda32f(A.hbuf + (size_t)((2*2+pn)*BB + b)*HH + tid);
  __syncthreads();
  const int d = tid&63, kg = tid>>6;
  const float* wr = A.wout + (size_t)d*HH + kg*64;
  const float* hh = sh + kg*64;
  float acc = 0.f;
  #pragma unroll
  for (int k=0;k<64;k+=4){ float4 w4=ld4(wr+k); float4 hv=*(const float4*)&hh[k];
    acc += w4.x*hv.x+w4.y*hv.y+w4.z*hv.z+w4.w*hv.w; }
  red[tid]=acc; __syncthreads();
  if (tid<64){
    float y = A.bout[tid];
    #pragma unroll
    for (int kk=0;kk<16;++kk) y += red[kk*64+tid];
    A.dout[((size_t)b*NSTEP+s)*DOUT+tid] = y;
    yv[tid] = y;
  }
  __syncthreads();
  if (tid < 32){
    float v0=yv[2*tid], v1=yv[2*tid+1];
    sta32((u32*)A.pl[0][pn] + xidx(NIT0, b, 32 + 2*tid),
          (u32)f2bf(v0) | ((u32)f2bf(v1)<<16));
  }
}

// MFMA GEMM (16 weight rows x 32 batch per block, 256 blocks) + fused cell.
// waves = xh(2) x kq(8); per-wave contiguous 1KB w + 1KB x per iter, 1 MFMA.
template<int L, int NIT>
__device__ void gemm_phase(const SeqArgs& A, int p, int pn, float* sm){
  const int bid = blockIdx.x, tid = threadIdx.x;
  const u16* wh = A.wwh[L];
  const u16* ih = A.pl[L][p];
  const int wave = tid>>6, lane = tid&63;
  const int xh = wave>>3, kq = wave&7;
  const size_t wbase = (((size_t)bid*8 + kq)*NIT)*512 + lane*8;
  const size_t xbase = (((size_t)xh*8 + kq)*NIT)*512 + lane*8;
  const u16* wph = wh + wbase;
  const u16* xb  = ih + xbase;

  f32x4 acc = {0.f,0.f,0.f,0.f};
  bf16x8 whA, whB;
  FR xhA, xhB;
  whA = *(const bf16x8*)(wph);
  xhA.q[0] = lda64(xb);    xhA.q[1] = lda64(xb+4);
  #pragma unroll
  for (int it = 0; it < NIT; ++it){
    const int o = (it+1)*512;
    if ((it & 1) == 0){
      if (it+1 < NIT){
        whB = *(const bf16x8*)(wph + o);
        xhB.q[0] = lda64(xb+o);  xhB.q[1] = lda64(xb+o+4);
      }
      acc = __builtin_amdgcn_mfma_f32_16x16x32_bf16(xhA.v, whA, acc, 0,0,0);
    } else {
      if (it+1 < NIT){
        whA = *(const bf16x8*)(wph + o);
        xhA.q[0] = lda64(xb+o);  xhA.q[1] = lda64(xb+o+4);
      }
      acc = __builtin_amdgcn_mfma_f32_16x16x32_bf16(xhB.v, whB, acc, 0,0,0);
    }
  }

  float* red = sm;            // 16*256
  float* sg  = sm + 4096;     // 16*32
  float* hv  = sm + 4608;     // 4*32
  #pragma unroll
  for (int rg=0; rg<4; ++rg) red[wave*256 + lane*4 + rg] = acc[rg];
  __syncthreads();
  if (tid < 512){
    const int xh2 = tid>>8, e = tid&255;
    float v = 0.f;
    #pragma unroll
    for (int k2=0; k2<8; ++k2) v += red[(xh2*8 + k2)*256 + e];
    const int ln = e>>2, rg = e&3;
    // D layout (m89): col=lane&15 -> weight row, row=4*(lane>>4)+reg -> batch
    sg[(ln&15)*32 + xh2*16 + ((ln>>4)<<2) + rg] = v;
  }
  __syncthreads();
  if (tid < 128){
    const int b = tid&31, jj = tid>>5;        // jj = 0..3
    const int j = bid*4 + jj;
    const float* bs = A.bsum[L];
    float gi = sg[(0 +jj)*32+b] + bs[j];
    float gf = sg[(4 +jj)*32+b] + bs[1024+j];
    float gg = sg[(8 +jj)*32+b] + bs[2048+j];
    float go = sg[(12+jj)*32+b] + bs[3072+j];
    float i_ = 1.f/(1.f+__expf(-gi));
    float f_ = 1.f/(1.f+__expf(-gf));
    float g_ = tanhf(gg);
    float o_ = 1.f/(1.f+__expf(-go));
    float* cb = A.cbuf + ((size_t)L*BB + b)*HH + j;
    float c = f_*cb[0] + i_*g_;
    cb[0] = c;
    float hval = o_*tanhf(c);
    sta32f(A.hbuf + ((size_t)(L*2+pn)*BB + b)*HH + j, hval);
    hv[jj*32 + b] = hval;
  }
  __syncthreads();
  if (tid < 64){
    const int b = tid&31, pr = tid>>5;        // pr = 0..1
    const int jj0 = pr*2;
    float v0 = hv[jj0*32+b], v1 = hv[(jj0+1)*32+b];
    u32 ph = (u32)f2bf(v0) | ((u32)f2bf(v1)<<16);
    const int col = bid*4 + jj0;
    if (L == 0){
      sta32((u32*)A.pl[0][pn] + xidx(NIT0,  b, 96 + col), ph);    // own h1
      sta32((u32*)A.pl[1][p ] + xidx(NIT12, b, 32 + col), ph);    // L2 input
    } else if (L == 1){
      sta32((u32*)A.pl[1][pn] + xidx(NIT12, b, 1056 + col), ph);  // own h2
      sta32((u32*)A.pl[2][p ] + xidx(NIT12, b, 32 + col), ph);    // L3 input
    } else {
      sta32((u32*)A.pl[2][pn] + xidx(NIT12, b, 1056 + col), ph);  // own h3
    }
  }
}

__global__ __launch_bounds__(1024, 4) void seq_kernel(SeqArgs A){
  __shared__ float sm[SMEM_FLOATS];
  const int bid = blockIdx.x, tid = threadIdx.x;
  const size_t gid = (size_t)bid*1024 + tid;
  const size_t gstr = (size_t)256*1024;
  u32 nb = 0;

  // ---- init: zero planes (incl pads), hbuf par0, cbuf ----
  {
    const size_t n0 = (size_t)32*(KP0>>1);      // u32 per l0 buffer
    const size_t n1 = (size_t)32*(KP12>>1);     // u32 per l1/l2 buffer
    for (size_t i = gid; i < n0; i += gstr){
      #pragma unroll
      for (int q=0;q<2;++q) sta32((u32*)A.pl[0][q] + i, 0u);
    }
    for (size_t i = gid; i < n1; i += gstr){
      #pragma unroll
      for (int q=0;q<2;++q){
        sta32((u32*)A.pl[1][q] + i, 0u);
        sta32((u32*)A.pl[2][q] + i, 0u);
      }
    }
  }
  for (size_t i = gid; i < (size_t)3*32*1024; i += gstr){
    size_t l2 = i >> 15, r = i & 32767, b = r >> 10, j = r & 1023;
    sta32f(A.hbuf + ((l2*2+0)*BB + b)*HH + j, 0.f);
  }
  {
    for (int t = tid; t < 3*32*4; t += 1024){
      int l2 = t>>7, r = t&127, b = r>>2, jj = r&3;
      A.cbuf[((size_t)l2*BB + b)*HH + bid*4 + jj] = 0.f;
    }
  }
  gbar(A, ++nb);

  // P0: att1/2/3(0) at parity 0 ; prev(0) = x[:,T-1,:] into l0 plane par0.
  if (bid >= 128 && bid < 224){
    int l = (bid-128)>>5, b = (bid-128)&31;
    attend_phase(A, l, 0, b, sm);
  } else if (bid >= 224){
    int b = bid - 224;
    if (tid < 64 && (tid & 1) == 0){
      float v  = A.x[((size_t)b*TT + (TT-1))*DIN + tid];
      float v1 = A.x[((size_t)b*TT + (TT-1))*DIN + tid + 1];
      sta32((u32*)A.pl[0][0] + xidx(NIT0, b, 32 + tid),
            (u32)f2bf(v) | ((u32)f2bf(v1)<<16));
    }
  }
  gbar(A, ++nb);

  for (int s = 0; s < NSTEP; ++s){
    const int p = s&1, pn = p^1;
    // P1: G1(s) on ALL 256 blocks
    gemm_phase<0,NIT0>(A, p, pn, sm);
    gbar(A, ++nb);
    // P2: G2(s) on ALL 256 blocks
    gemm_phase<1,NIT12>(A, p, pn, sm);
    gbar(A, ++nb);
    // P3: G3(s) on ALL 256 blocks
    gemm_phase<2,NIT12>(A, p, pn, sm);
    gbar(A, ++nb);
    // P4: att1/att2/att3(s+1) + out(s) on 128 blocks
    if (bid >= 128 && bid < 224){
      int l = (bid-128)>>5, b = (bid-128)&31;
      attend_phase(A, l, pn, b, sm);
    } else if (bid >= 224){
      out_phase(A, pn, s, bid-224, sm);
    }
    gbar(A, ++nb);
  }
}

// ---------------------------------------------------------------------------
extern "C" void kernel_launch(void* const* d_in, const int* in_sizes, int n_in,
                              void* d_out, int out_size, void* d_ws, size_t ws_size,
                              hipStream_t stream) {
  const float* x    = (const float*)d_in[0];
  const float* w_c1 = (const float*)d_in[1];
  const float* b_c1 = (const float*)d_in[2];
  const float* w_c2 = (const float*)d_in[3];
  const float* b_c2 = (const float*)d_in[4];
  const float* w_c3 = (const float*)d_in[5];
  const float* b_c3 = (const float*)d_in[6];

  SeqArgs A;
  A.x     = x;
  A.wa[0] = (const float*)d_in[7];
  A.wa[1] = (const float*)d_in[9];
  A.wa[2] = (const float*)d_in[11];
  const float* wih1 = (const float*)d_in[13];
  const float* whh1 = (const float*)d_in[14];
  const float* bih1 = (const float*)d_in[15];
  const float* bhh1 = (const float*)d_in[16];
  const float* wih2 = (const float*)d_in[17];
  const float* whh2 = (const float*)d_in[18];
  const float* bih2 = (const float*)d_in[19];
  const float* bhh2 = (const float*)d_in[20];
  const float* wih3 = (const float*)d_in[21];
  const float* whh3 = (const float*)d_in[22];
  const float* bih3 = (const float*)d_in[23];
  const float* bhh3 = (const float*)d_in[24];
  A.wout = (const float*)d_in[25];
  A.bout = (const float*)d_in[26];
  A.dout = (float*)d_out;

  char* base = (char*)d_ws;
  size_t off = 0;
  auto alloc = [&](size_t bytes)->char*{
    char* pp = base + off; off = (off + bytes + 255) & ~(size_t)255; return pp;
  };

  u16* enc = (u16*)alloc((size_t)BB*LL3*CC3*2);
  A.enc  = enc;
  A.hbuf = (float*)alloc((size_t)3*2*BB*HH*4);
  A.cbuf = (float*)alloc((size_t)3*BB*HH*4);
  for (int l=0;l<3;++l){
    size_t kp = (l==0)? KP0 : KP12;
    for (int par=0; par<2; ++par)
      A.pl[l][par] = (u16*)alloc((size_t)BB*kp*2);
  }
  float* bs0 = (float*)alloc(4096*4);
  float* bs1 = (float*)alloc(4096*4);
  float* bs2 = (float*)alloc(4096*4);
  A.bsum[0]=bs0; A.bsum[1]=bs1; A.bsum[2]=bs2;
  u32* bar = (u32*)alloc(4096);
  A.slots = bar;
  A.go    = bar + 320;
  u16 *wp[3];
  wp[0] = (u16*)alloc((size_t)4096*KP0*2);     // 10.5 MB
  wp[1] = (u16*)alloc((size_t)4096*KP12*2);    // 18.9 MB
  wp[2] = (u16*)alloc((size_t)4096*KP12*2);
  A.wwh[0]=wp[0]; A.wwh[1]=wp[1]; A.wwh[2]=wp[2];

  // conv temps alias the layer-1 weight buffer (preps run after convs)
  float* r1 = (float*)wp[0];                         // 2.09 MB
  float* r2 = (float*)(((char*)wp[0]) + 2095104);    // 4.17 MB (< 10.4 MB)

  conv1_kernel<<<(BB*LL1+255)/256, 256, 0, stream>>>(x, w_c1, b_c1, r1);
  conv2_kernel<<<(BB*LL2+255)/256, 256, 0, stream>>>(r1, w_c2, b_c2, r2);
  conv3_kernel<<<(BB*LL3+255)/256, 256, 0, stream>>>(r2, w_c3, b_c3, enc);
  prep_kernel<<<2048, 256, 0, stream>>>(wih1, whh1, wp[0],   96, K0,  NIT0);
  prep_kernel<<<2048, 256, 0, stream>>>(wih2, whh2, wp[1], 1056, K12, NIT12);
  prep_kernel<<<2048, 256, 0, stream>>>(wih3, whh3, wp[2], 1056, K12, NIT12);
  bsum_kernel<<<48, 256, 0, stream>>>(bih1,bhh1,bih2,bhh2,bih3,bhh3, bs0,bs1,bs2);
  barinit_kernel<<<1, 256, 0, stream>>>(bar);

  void* params[] = { (void*)&A };
  hipLaunchCooperativeKernel((const void*)seq_kernel, dim3(256), dim3(1024),
                             params, 0, stream);
}